// Round 15
// baseline (419.100 us; speedup 1.0000x reference)
//
#include <hip/hip_runtime.h>
#include <hip/hip_cooperative_groups.h>
#include <hip/hip_bf16.h>
#include <math.h>

namespace cg = cooperative_groups;

// Problem constants (fixed by the reference)
#define NNODES 4096
#define NFEAT_ 1024
#define NHID_  64
#define NHEADS_ 8
#define EMB_   512
#define MAXD   256
constexpr float ALPHA_ = 0.2f;

typedef __attribute__((ext_vector_type(8))) short bf16x8;  // 8 bf16 (4 VGPRs)
typedef __attribute__((ext_vector_type(4))) float f32x4;   // MFMA accumulator
typedef unsigned int u32;
typedef unsigned short u16;

__device__ inline u16 f2b(float f) {
    __hip_bfloat16 b = __float2bfloat16(f);
    return *(u16*)&b;
}
__device__ inline float b2f(u16 u) {
    return __uint_as_float(((u32)u) << 16);
}

// async global->LDS, 16 B per lane. LDS dest: wave-uniform base + lane*16.
__device__ inline void cp16(const void* g, void* l) {
    __builtin_amdgcn_global_load_lds(
        (const __attribute__((address_space(1))) u32*)g,
        (__attribute__((address_space(3))) u32*)l, 16, 0, 0);
}

// ---------------------------------------------------------------------------
// Device-side bf16 MFMA GEMM tile:  C[M,N] = act( A[M,K] @ B[N,K]^T + bias )
// Same body as the r10-measured gemm_bt (double-buffered global_load_lds,
// one __syncthreads per K-step). bid in [0,512): m0=(bid>>3)*BM, n0=(bid&7)*BN
// (every decoder layer has exactly 8 n-tiles). As/Bs are caller LDS
// ([2][BM*32] / [2][BN*32] flat).
// ---------------------------------------------------------------------------
template<int BM, int BN, int OUTM, int ACT>
__device__ __forceinline__ void gemm_tile(
    u16* __restrict__ As, u16* __restrict__ Bs,
    const u16* __restrict__ A, const u16* __restrict__ B,
    const float* __restrict__ bias, void* __restrict__ Cv,
    int N, int K, int bid)
{
    constexpr int BK  = 32;
    constexpr int WM  = BM / 2;
    constexpr int MI  = WM / 16;
    constexpr int WN  = BN / 2;
    constexpr int NJ  = WN / 16;
    constexpr int ACH = BM / 16;
    constexpr int BCH = BN / 16;
    constexpr int ASZ = BM * BK, BSZ = BN * BK;

    const int tid  = threadIdx.x;
    const int wid  = tid >> 6, lane = tid & 63;
    const int wr   = wid >> 1, wc = wid & 1;
    const int m0   = (bid >> 3) * BM, n0 = (bid & 7) * BN;
    const int frow = lane & 15, fk = (lane >> 4) * 8;
    const int lr   = lane >> 2, lc = (lane & 3) * 8;

    auto stage = [&](int buf, int k0) {
        const u16* gA = A + (long)m0 * K + k0;
        {
            int c = wid;
            cp16(gA + (long)(c * 16 + lr) * K + lc, &As[buf * ASZ + c * 512]);
            if (ACH == 8) {
                c = wid + 4;
                cp16(gA + (long)(c * 16 + lr) * K + lc, &As[buf * ASZ + c * 512]);
            }
        }
        const u16* gB = B + (long)n0 * K + k0;
        if (BCH >= 4) {
            int c = wid;
            cp16(gB + (long)(c * 16 + lr) * K + lc, &Bs[buf * BSZ + c * 512]);
            if (BCH == 8) {
                c = wid + 4;
                cp16(gB + (long)(c * 16 + lr) * K + lc, &Bs[buf * BSZ + c * 512]);
            }
        } else if (wid < BCH) {
            cp16(gB + (long)(wid * 16 + lr) * K + lc, &Bs[buf * BSZ + wid * 512]);
        }
    };

    f32x4 acc[MI][NJ] = {};

    stage(0, 0);
    __syncthreads();
    int cur = 0;
    for (int k0 = 0; k0 < K; k0 += BK) {
        if (k0 + BK < K) stage(cur ^ 1, k0 + BK);

        bf16x8 af[MI], bfr[NJ];
        #pragma unroll
        for (int i = 0; i < MI; ++i)
            af[i] = *(const bf16x8*)&As[cur * ASZ + (wr * WM + i * 16 + frow) * BK + fk];
        #pragma unroll
        for (int j = 0; j < NJ; ++j)
            bfr[j] = *(const bf16x8*)&Bs[cur * BSZ + (wc * WN + j * 16 + frow) * BK + fk];
        #pragma unroll
        for (int i = 0; i < MI; ++i)
            #pragma unroll
            for (int j = 0; j < NJ; ++j)
                acc[i][j] = __builtin_amdgcn_mfma_f32_16x16x32_bf16(
                    af[i], bfr[j], acc[i][j], 0, 0, 0);

        __syncthreads();
        cur ^= 1;
    }

    // epilogue: C/D layout col=lane&15, row=(lane>>4)*4+reg  [m89-verified]
    const int crow0 = m0 + wr * WM + (lane >> 4) * 4;
    const int ccol0 = n0 + wc * WN + (lane & 15);
    #pragma unroll
    for (int i = 0; i < MI; ++i)
        #pragma unroll
        for (int j = 0; j < NJ; ++j)
            #pragma unroll
            for (int r = 0; r < 4; ++r) {
                const int row = crow0 + i * 16 + r;
                const int col = ccol0 + j * 16;
                float v = acc[i][j][r];
                if (bias) v += bias[col];
                if (ACT == 1) v = v > 0.f ? v : 0.f;
                if (OUTM == 1) ((u16*)Cv)[(long)row * N + col] = f2b(v);
                else           ((float*)Cv)[(long)row * N + col] = v;
            }
}

// ---------------------------------------------------------------------------
// Fused decoder: all 4 MLP layers in ONE cooperative kernel, grid.sync()
// between layers. All layers use the same 512-block grid (8 n-tiles each),
// 2 blocks/CU co-resident. Removes 3 launch gaps + 3 drain/refill cycles.
// ---------------------------------------------------------------------------
__global__ __launch_bounds__(256) void decoder_fused(
    const u16* __restrict__ enc,
    const u16* __restrict__ W1b, const float* __restrict__ b1, u16* __restrict__ dd1,
    const u16* __restrict__ W2b, const float* __restrict__ b2, u16* __restrict__ dd2,
    const u16* __restrict__ W3b, const float* __restrict__ b3, u16* __restrict__ dd3,
    const u16* __restrict__ W4b, const float* __restrict__ b4, float* __restrict__ out)
{
    __shared__ __align__(16) u16 As[2 * 64 * 32];    //  8 KB (BM=64)
    __shared__ __align__(16) u16 Bs[2 * 128 * 32];   // 16 KB (max BN=128)
    cg::grid_group grid = cg::this_grid();
    const int bid = blockIdx.x;

    gemm_tile<64, 32, 1, 1>(As, Bs, enc, W1b, b1, dd1, 256, 512, bid);
    grid.sync();
    gemm_tile<64, 32, 1, 1>(As, Bs, dd1, W2b, b2, dd2, 256, 256, bid);
    grid.sync();
    gemm_tile<64, 64, 1, 1>(As, Bs, dd2, W3b, b3, dd3, 512, 256, bid);
    grid.sync();
    gemm_tile<64, 128, 0, 0>(As, Bs, dd3, W4b, b4, out, 1024, 512, bid);
}

// ---------------------------------------------------------------------------
// Head GEMM (Whb = xb @ WcT^T, bf16 out, fused e_src/e_dst^T epilogue)
// FUSED with the neighbor-list build (nbr blocks are pure HBM and overlap
// the compute/L2-bound GEMM blocks).
//   blocks [0, 512)      : GEMM tile (m0 = (b>>3)*64, n0 = (b&7)*64)
//   blocks [512, 4608)   : neighbor list for row b-512
// ---------------------------------------------------------------------------
__global__ __launch_bounds__(256) void head_gemm_nbr(
    const u16* __restrict__ A, const u16* __restrict__ B,
    u16* __restrict__ Whb,
    const float* __restrict__ a1, const float* __restrict__ a2,
    float* __restrict__ es, float* __restrict__ edT,
    const float* __restrict__ adj, int* __restrict__ cnt,
    int* __restrict__ nbr)
{
    constexpr int BM = 64, BN = 64, BK = 32;
    constexpr int WM = 32, MI = 2, WN = 32, NJ = 2;
    constexpr int N = EMB_, K = NFEAT_;

    __shared__ __align__(16) u16 As[2][BM * BK];
    __shared__ __align__(16) u16 Bs[2][BN * BK];
    __shared__ float s1Lds[2][BM];
    __shared__ float s2Lds[2][BM];
    __shared__ int lcnt;

    const int bid = blockIdx.x;
    const int tid = threadIdx.x;

    if (bid >= 512) {
        // ---- neighbor list for row n = bid - 512 ----
        const int n = bid - 512;
        if (tid == 0) lcnt = 0;
        __syncthreads();
        const float4* arow = (const float4*)(adj + (long)n * NNODES);
        for (int m4 = tid; m4 < NNODES / 4; m4 += 256) {
            const float4 v = arow[m4];
            if (v.x != 0.f) { const int p = atomicAdd(&lcnt, 1); if (p < MAXD) nbr[n * MAXD + p] = m4 * 4; }
            if (v.y != 0.f) { const int p = atomicAdd(&lcnt, 1); if (p < MAXD) nbr[n * MAXD + p] = m4 * 4 + 1; }
            if (v.z != 0.f) { const int p = atomicAdd(&lcnt, 1); if (p < MAXD) nbr[n * MAXD + p] = m4 * 4 + 2; }
            if (v.w != 0.f) { const int p = atomicAdd(&lcnt, 1); if (p < MAXD) nbr[n * MAXD + p] = m4 * 4 + 3; }
        }
        __syncthreads();
        if (tid == 0) cnt[n] = lcnt < MAXD ? lcnt : MAXD;
        return;
    }

    // ---- GEMM tile ----
    const int wid  = tid >> 6, lane = tid & 63;
    const int wr   = wid >> 1, wc = wid & 1;
    const int m0   = (bid >> 3) * BM, n0 = (bid & 7) * BN;
    const int frow = lane & 15, fk = (lane >> 4) * 8;
    const int lr   = lane >> 2, lc = (lane & 3) * 8;

    auto stage = [&](int buf, int k0) {
        const u16* gA = A + (long)m0 * K + k0;
        cp16(gA + (long)(wid * 16 + lr) * K + lc, &As[buf][wid * 512]);
        const u16* gB = B + (long)n0 * K + k0;
        cp16(gB + (long)(wid * 16 + lr) * K + lc, &Bs[buf][wid * 512]);
    };

    f32x4 acc[MI][NJ] = {};

    stage(0, 0);
    __syncthreads();
    int cur = 0;
    for (int k0 = 0; k0 < K; k0 += BK) {
        if (k0 + BK < K) stage(cur ^ 1, k0 + BK);

        bf16x8 af[MI], bfr[NJ];
        #pragma unroll
        for (int i = 0; i < MI; ++i)
            af[i] = *(const bf16x8*)&As[cur][(wr * WM + i * 16 + frow) * BK + fk];
        #pragma unroll
        for (int j = 0; j < NJ; ++j)
            bfr[j] = *(const bf16x8*)&Bs[cur][(wc * WN + j * 16 + frow) * BK + fk];
        #pragma unroll
        for (int i = 0; i < MI; ++i)
            #pragma unroll
            for (int j = 0; j < NJ; ++j)
                acc[i][j] = __builtin_amdgcn_mfma_f32_16x16x32_bf16(
                    af[i], bfr[j], acc[i][j], 0, 0, 0);

        __syncthreads();
        cur ^= 1;
    }

    // epilogue: Whb bf16 write
    const int crow0 = m0 + wr * WM + (lane >> 4) * 4;
    const int ccol0 = n0 + wc * WN + (lane & 15);
    #pragma unroll
    for (int i = 0; i < MI; ++i)
        #pragma unroll
        for (int j = 0; j < NJ; ++j)
            #pragma unroll
            for (int r = 0; r < 4; ++r)
                Whb[(long)(crow0 + i * 16 + r) * N + ccol0 + j * 16] =
                    f2b(acc[i][j][r]);

    // fused e_src / e_dst^T from fp32 accumulators (head h = n0/64)
    const int h = n0 >> 6;
    const float a1v0 = a1[h * 64 + wc * WN + frow];
    const float a1v1 = a1[h * 64 + wc * WN + 16 + frow];
    const float a2v0 = a2[h * 64 + wc * WN + frow];
    const float a2v1 = a2[h * 64 + wc * WN + 16 + frow];
    #pragma unroll
    for (int i = 0; i < MI; ++i)
        #pragma unroll
        for (int r = 0; r < 4; ++r) {
            float s1 = acc[i][0][r] * a1v0 + acc[i][1][r] * a1v1;
            float s2 = acc[i][0][r] * a2v0 + acc[i][1][r] * a2v1;
            #pragma unroll
            for (int off = 8; off; off >>= 1) {
                s1 += __shfl_xor(s1, off);
                s2 += __shfl_xor(s2, off);
            }
            if (frow == 0) {
                const int row = wr * WM + i * 16 + (lane >> 4) * 4 + r;
                s1Lds[wc][row] = s1;
                s2Lds[wc][row] = s2;
            }
        }
    __syncthreads();
    if (tid < BM) {
        es[h * NNODES + m0 + tid] = s1Lds[0][tid] + s1Lds[1][tid];
        edT[(m0 + tid) * NHEADS_ + h] = s2Lds[0][tid] + s2Lds[1][tid];
    }
}

// ---------------------------------------------------------------------------
// Prep: bf16 casts of x / decoder weights + WcT tile-transpose.
//   blocks [0, 512)   : casts (grid-stride)
//   blocks [512, 640) : WcT[h*64+d][k] = W[h][k][d] (64x64 LDS transpose)
// ---------------------------------------------------------------------------
#define CASTB 512
__global__ __launch_bounds__(256) void prep(
    const float* __restrict__ x,   const float* __restrict__ W,
    const float* __restrict__ W1,  const float* __restrict__ W2,
    const float* __restrict__ W3,  const float* __restrict__ W4,
    u16* __restrict__ xb,  u16* __restrict__ WcT,
    u16* __restrict__ W1b, u16* __restrict__ W2b,
    u16* __restrict__ W3b, u16* __restrict__ W4b)
{
    const int b = blockIdx.x, tid = threadIdx.x;

    if (b < CASTB) {
        const int np = CASTB * 256;
        const int t = b * 256 + tid;
        for (int i = t; i < (NNODES * NFEAT_) / 4; i += np) {
            const float4 v = ((const float4*)x)[i];
            ushort4 o; o.x = f2b(v.x); o.y = f2b(v.y); o.z = f2b(v.z); o.w = f2b(v.w);
            ((ushort4*)xb)[i] = o;
        }
        for (int i = t; i < (256 * 512) / 4; i += np) {
            const float4 v = ((const float4*)W1)[i];
            ushort4 o; o.x = f2b(v.x); o.y = f2b(v.y); o.z = f2b(v.z); o.w = f2b(v.w);
            ((ushort4*)W1b)[i] = o;
        }
        for (int i = t; i < (256 * 256) / 4; i += np) {
            const float4 v = ((const float4*)W2)[i];
            ushort4 o; o.x = f2b(v.x); o.y = f2b(v.y); o.z = f2b(v.z); o.w = f2b(v.w);
            ((ushort4*)W2b)[i] = o;
        }
        for (int i = t; i < (512 * 256) / 4; i += np) {
            const float4 v = ((const float4*)W3)[i];
            ushort4 o; o.x = f2b(v.x); o.y = f2b(v.y); o.z = f2b(v.z); o.w = f2b(v.w);
            ((ushort4*)W3b)[i] = o;
        }
        for (int i = t; i < (1024 * 512) / 4; i += np) {
            const float4 v = ((const float4*)W4)[i];
            ushort4 o; o.x = f2b(v.x); o.y = f2b(v.y); o.z = f2b(v.z); o.w = f2b(v.w);
            ((ushort4*)W4b)[i] = o;
        }
    } else {
        __shared__ float tile[64][65];
        const int tb = b - CASTB;
        const int h = tb >> 4, k0 = (tb & 15) * 64;
        #pragma unroll
        for (int p = 0; p < 4; ++p) {
            const int kr = p * 16 + (tid >> 4), d = (tid & 15) * 4;
            const float4 v = *(const float4*)&W[((long)h * NFEAT_ + k0 + kr) * NHID_ + d];
            tile[kr][d] = v.x; tile[kr][d + 1] = v.y;
            tile[kr][d + 2] = v.z; tile[kr][d + 3] = v.w;
        }
        __syncthreads();
        #pragma unroll
        for (int p = 0; p < 4; ++p) {
            const int d = p * 16 + (tid >> 4), k = (tid & 15) * 4;
            ushort4 o;
            o.x = f2b(tile[k][d]);     o.y = f2b(tile[k + 1][d]);
            o.z = f2b(tile[k + 2][d]); o.w = f2b(tile[k + 3][d]);
            *(ushort4*)&WcT[((long)h * 64 + d) * NFEAT_ + k0 + k] = o;
        }
    }
}

// ---------------------------------------------------------------------------
// Sparse masked softmax + aggregation + ELU -> enc (bf16, [N, H*nhid]).
// One block per node n (512 threads = 8 waves, wave h = head h).
// ---------------------------------------------------------------------------
__global__ __launch_bounds__(512) void attn_agg(
    const u16* __restrict__ Whb, const float* __restrict__ esrc,
    const float* __restrict__ edT, const int* __restrict__ cnt,
    const int* __restrict__ nbr, u16* __restrict__ enc)
{
    __shared__ __align__(16) int   mLds[MAXD];
    __shared__ __align__(16) float pLds[NHEADS_][MAXD];
    const int h = threadIdx.x >> 6, lane = threadIdx.x & 63;
    const int n = blockIdx.x;

    const int deg  = min(cnt[n], MAXD);
    const int degp = (deg + 15) & ~15;           // padded length (<= MAXD)

    // wave 0: stage neighbor list (+ zero padding) into LDS
    if (h == 0) {
        const int* lst = nbr + n * MAXD;
        for (int j = lane; j < deg; j += 64) mLds[j] = lst[j];
        for (int j = deg + lane; j < degp; j += 64) mLds[j] = 0;
    }
    __syncthreads();

    const float es = esrc[h * NNODES + n];

    float mymax = -3.4e38f;
    for (int j = lane; j < deg; j += 64) {
        float ev = es + edT[mLds[j] * NHEADS_ + h];
        ev = ev > 0.f ? ev : ALPHA_ * ev;
        pLds[h][j] = ev;
        mymax = fmaxf(mymax, ev);
    }
    for (int j = deg + lane; j < degp; j += 64) pLds[h][j] = 0.f;
    #pragma unroll
    for (int off = 32; off; off >>= 1) mymax = fmaxf(mymax, __shfl_xor(mymax, off));

    float mysum = 0.f;
    for (int j = lane; j < deg; j += 64) {
        const float p = __expf(pLds[h][j] - mymax);
        pLds[h][j] = p;
        mysum += p;
    }
    #pragma unroll
    for (int off = 32; off; off >>= 1) mysum += __shfl_xor(mysum, off);

    __syncthreads();

    // Phase 2: lane == output dim d within head h. 16 gathers in flight.
    float acc = 0.f;
    const u16* base = Whb + h * NHID_ + lane;
    for (int j0 = 0; j0 < degp; j0 += 16) {
        const int4   ma = *(const int4*)&mLds[j0];
        const int4   mb = *(const int4*)&mLds[j0 + 4];
        const int4   mc = *(const int4*)&mLds[j0 + 8];
        const int4   md = *(const int4*)&mLds[j0 + 12];
        const float4 pa = *(const float4*)&pLds[h][j0];
        const float4 pb = *(const float4*)&pLds[h][j0 + 4];
        const float4 pc = *(const float4*)&pLds[h][j0 + 8];
        const float4 pd = *(const float4*)&pLds[h][j0 + 12];
        const float v0  = b2f(base[(long)ma.x << 9]);
        const float v1  = b2f(base[(long)ma.y << 9]);
        const float v2  = b2f(base[(long)ma.z << 9]);
        const float v3  = b2f(base[(long)ma.w << 9]);
        const float v4  = b2f(base[(long)mb.x << 9]);
        const float v5  = b2f(base[(long)mb.y << 9]);
        const float v6  = b2f(base[(long)mb.z << 9]);
        const float v7  = b2f(base[(long)mb.w << 9]);
        const float v8  = b2f(base[(long)mc.x << 9]);
        const float v9  = b2f(base[(long)mc.y << 9]);
        const float v10 = b2f(base[(long)mc.z << 9]);
        const float v11 = b2f(base[(long)mc.w << 9]);
        const float v12 = b2f(base[(long)md.x << 9]);
        const float v13 = b2f(base[(long)md.y << 9]);
        const float v14 = b2f(base[(long)md.z << 9]);
        const float v15 = b2f(base[(long)md.w << 9]);
        acc = fmaf(pa.x, v0,  acc); acc = fmaf(pa.y, v1,  acc);
        acc = fmaf(pa.z, v2,  acc); acc = fmaf(pa.w, v3,  acc);
        acc = fmaf(pb.x, v4,  acc); acc = fmaf(pb.y, v5,  acc);
        acc = fmaf(pb.z, v6,  acc); acc = fmaf(pb.w, v7,  acc);
        acc = fmaf(pc.x, v8,  acc); acc = fmaf(pc.y, v9,  acc);
        acc = fmaf(pc.z, v10, acc); acc = fmaf(pc.w, v11, acc);
        acc = fmaf(pd.x, v12, acc); acc = fmaf(pd.y, v13, acc);
        acc = fmaf(pd.z, v14, acc); acc = fmaf(pd.w, v15, acc);
    }

    float hv = acc / mysum;
    hv = hv > 0.f ? hv : expm1f(hv);                       // ELU
    enc[(long)n * EMB_ + h * NHID_ + lane] = f2b(hv);
}

// ---------------------------------------------------------------------------
extern "C" void kernel_launch(void* const* d_in, const int* in_sizes, int n_in,
                              void* d_out, int out_size, void* d_ws, size_t ws_size,
                              hipStream_t stream)
{
    const float* x   = (const float*)d_in[0];
    const float* adj = (const float*)d_in[1];
    const float* W   = (const float*)d_in[2];
    const float* a1  = (const float*)d_in[3];
    const float* a2  = (const float*)d_in[4];
    const float* W1  = (const float*)d_in[5];
    const float* b1  = (const float*)d_in[6];
    const float* W2  = (const float*)d_in[7];
    const float* b2  = (const float*)d_in[8];
    const float* W3  = (const float*)d_in[9];
    const float* b3  = (const float*)d_in[10];
    const float* W4  = (const float*)d_in[11];
    const float* b4  = (const float*)d_in[12];
    float* out = (float*)d_out;

    // Workspace layout (16B-aligned offsets). dd1..dd3 alias xb (dead after
    // the head GEMM).
    float* es  = (float*)d_ws;                        //    32,768 f
    float* edT = es + 32768;                          //    32,768 f  [n][8]
    u16* Whb = (u16*)(edT + 32768);                   // 2,097,152 us (4 MB)
    u16* enc = Whb + 2097152;                         // 2,097,152 us
    u16* WcT = enc + 2097152;                         //   524,288 us
    u16* W1b = WcT + 524288;                          //   131,072 us
    u16* W2b = W1b + 131072;                          //    65,536 us
    u16* W3b = W2b + 65536;                           //   131,072 us
    u16* W4b = W3b + 131072;                          //   524,288 us
    int* cnt = (int*)(W4b + 524288);                  //     4,096 i
    int* nbr = cnt + 4096;                            // 1,048,576 i
    u16* xb  = (u16*)(nbr + 1048576);                 // 4,194,304 us (8 MB)
    u16* dd1 = xb;                                    // 1,048,576 us (alias)
    u16* dd2 = dd1 + 1048576;                         // 1,048,576 us
    u16* dd3 = dd2 + 1048576;                         // 2,097,152 us

    // 0) prep: bf16 casts + WcT transpose
    prep<<<dim3(CASTB + 128), 256, 0, stream>>>(
        x, W, W1, W2, W3, W4, xb, WcT, W1b, W2b, W3b, W4b);

    // 1) head GEMM (-> Whb + es/edT) fused with the adjacency scan
    head_gemm_nbr<<<dim3(512 + NNODES), 256, 0, stream>>>(
        xb, WcT, Whb, a1, a2, es, edT, adj, cnt, nbr);

    // 2) sparse softmax + aggregate + ELU -> enc (bf16); block per node
    attn_agg<<<dim3(NNODES), 512, 0, stream>>>(Whb, es, edT, cnt, nbr, enc);

    // 3) fused decoder MLP: one cooperative kernel, grid.sync between layers
    {
        const u16* enc_c = enc;
        void* kargs[] = {
            (void*)&enc_c,
            (void*)&W1b, (void*)&b1, (void*)&dd1,
            (void*)&W2b, (void*)&b2, (void*)&dd2,
            (void*)&W3b, (void*)&b3, (void*)&dd3,
            (void*)&W4b, (void*)&b4, (void*)&out
        };
        hipLaunchCooperativeKernel((const void*)decoder_fused,
                                   dim3(512), dim3(256), kargs, 0, stream);
    }
}